// Round 5
// baseline (214.825 us; speedup 1.0000x reference)
//
#include <hip/hip_runtime.h>
#include <hip/hip_bf16.h>
#include <stdint.h>

typedef short bf16x8 __attribute__((ext_vector_type(8)));
typedef float f32x4 __attribute__((ext_vector_type(4)));
typedef float f32x16 __attribute__((ext_vector_type(16)));
typedef unsigned short u16;

#define GLOAD16(gp, lp)                                                        \
  __builtin_amdgcn_global_load_lds(                                            \
      (const __attribute__((address_space(1))) void*)(gp),                     \
      (__attribute__((address_space(3))) void*)(lp), 16, 0, 0)

__device__ __forceinline__ u16 f2bf(float f) {
  uint32_t u = __builtin_bit_cast(uint32_t, f);
  u = (u + 0x7FFFu + ((u >> 16) & 1u)) >> 16;
  return (u16)u;
}

// physical byte offset within an LDS region for logical (row, 16B-unit u∈0..3)
__device__ __forceinline__ int swzoff(int row, int u) {
  int p = row >> 1;
  int us = ((row & 1) * 4 + u) ^ (p & 7);
  return p * 128 + us * 16;
}

// ================= mega pre-pass: all packing + router in ONE launch ========
__global__ void mega(const float* __restrict__ x, const float* __restrict__ rw,
                     const float* __restrict__ eg, const float* __restrict__ eu,
                     const float* __restrict__ ed, const float* __restrict__ sg,
                     const float* __restrict__ su, const float* __restrict__ sd,
                     u16* __restrict__ Xb, u16* __restrict__ WpT,
                     u16* __restrict__ WdT, float* __restrict__ coef) {
  __shared__ float t[64][65];
  const int tid = threadIdx.x;
  const int b = blockIdx.x;
  if (b < 1280) {
    const float* src; int kbase, kt, ht;
    if (b < 1024) { src = ed; kbase = 0;    kt = b >> 4;          ht = b & 15; }
    else          { src = sd; kbase = 4096; kt = (b - 1024) >> 4; ht = b & 15; }
    const int k0 = kt * 64, h0 = ht * 64;
#pragma unroll
    for (int p = 0; p < 4; ++p) {
      int r = p * 16 + (tid >> 4), c = (tid & 15) * 4;
      float4 v = *(const float4*)&src[(size_t)(k0 + r) * 1024 + h0 + c];
      t[r][c] = v.x; t[r][c + 1] = v.y; t[r][c + 2] = v.z; t[r][c + 3] = v.w;
    }
    __syncthreads();
#pragma unroll
    for (int p = 0; p < 4; ++p) {
      int hl = p * 16 + (tid >> 4), kl = (tid & 15) * 4;
      ushort4 o;
      o.x = f2bf(t[kl][hl]);     o.y = f2bf(t[kl + 1][hl]);
      o.z = f2bf(t[kl + 2][hl]); o.w = f2bf(t[kl + 3][hl]);
      *(ushort4*)&WdT[(size_t)(h0 + hl) * 5120 + kbase + k0 + kl] = o;
    }
  } else if (b < 3840) {
    int bb = b - 1280;
    const float* src; int pbase, C, dt, ht;
    if (bb < 2048) {
      int slice = bb >> 7, r = bb & 127;
      int e = slice >> 1; int up = slice & 1;
      src = (up ? eu : eg) + (size_t)e * 524288;
      pbase = e * 1024 + up * 32; C = 512;
      dt = r >> 4; ht = r & 15;
    } else {
      int r = bb - 2048;
      int up = r >= 256; r &= 255;
      src = up ? su : sg; pbase = 8192 + up * 32; C = 1024;
      dt = r >> 4; ht = r & 15;
    }
    const int d0 = dt * 64, h0 = ht * 64;
#pragma unroll
    for (int p = 0; p < 4; ++p) {
      int hl = p * 16 + (tid >> 4), dl = (tid & 15) * 4;
      float4 v = *(const float4*)&src[(size_t)(h0 + hl) * C + d0 + dl];
      t[hl][dl] = v.x; t[hl][dl + 1] = v.y; t[hl][dl + 2] = v.z; t[hl][dl + 3] = v.w;
    }
    __syncthreads();
#pragma unroll
    for (int p = 0; p < 4; ++p) {
      int dl = p * 16 + (tid >> 4), hl = (tid & 15) * 4;
      int d = d0 + dl;
      int prow = pbase + ((d >> 5) << 6) + (d & 31);
      ushort4 o;
      o.x = f2bf(t[hl][dl]);     o.y = f2bf(t[hl + 1][dl]);
      o.z = f2bf(t[hl + 2][dl]); o.w = f2bf(t[hl + 3][dl]);
      *(ushort4*)&WpT[(size_t)prow * 1024 + h0 + hl] = o;
    }
  } else if (b < 4864) {
    const int l = tid & 63;
    const int tok = (b - 3840) * 4 + (tid >> 6);
    const float* xr = x + (size_t)tok * 1024;
    float acc[8];
#pragma unroll
    for (int e = 0; e < 8; ++e) acc[e] = 0.f;
    for (int it = 0; it < 16; ++it) {
      int h = it * 64 + l;
      float xv = xr[h];
      float4 r0 = *(const float4*)&rw[h * 8];
      float4 r1 = *(const float4*)&rw[h * 8 + 4];
      acc[0] += xv * r0.x; acc[1] += xv * r0.y; acc[2] += xv * r0.z; acc[3] += xv * r0.w;
      acc[4] += xv * r1.x; acc[5] += xv * r1.y; acc[6] += xv * r1.z; acc[7] += xv * r1.w;
    }
#pragma unroll
    for (int off = 32; off >= 1; off >>= 1) {
#pragma unroll
      for (int e = 0; e < 8; ++e) acc[e] += __shfl_xor(acc[e], off, 64);
    }
    if (l == 0) {
      float m = acc[0];
#pragma unroll
      for (int e = 1; e < 8; ++e) m = fmaxf(m, acc[e]);
      float p[8], s = 0.f;
#pragma unroll
      for (int e = 0; e < 8; ++e) { p[e] = expf(acc[e] - m); s += p[e]; }
      int i1 = 0;
#pragma unroll
      for (int e = 1; e < 8; ++e) if (p[e] > p[i1]) i1 = e;
      int i2 = (i1 == 0) ? 1 : 0;
#pragma unroll
      for (int e = 0; e < 8; ++e) if (e != i1 && p[e] > p[i2]) i2 = e;
      float inv = 1.f / s;
#pragma unroll
      for (int e = 0; e < 8; ++e) coef[tok * 8 + e] = (e == i1 || e == i2) ? p[e] * inv : 0.f;
    }
  } else {
    int i = (b - 4864) * 512 + tid;
#pragma unroll
    for (int k = 0; k < 2; ++k) {
      float4 v = ((const float4*)x)[i + k * 256];
      ushort4 o;
      o.x = f2bf(v.x); o.y = f2bf(v.y); o.z = f2bf(v.z); o.w = f2bf(v.w);
      ((ushort4*)Xb)[i + k * 256] = o;
    }
  }
}

// ===== counted-vmcnt pipelined GEMM, 32x32x16 MFMA, reg-dbuf frag prefetch ==
template <int BM, int BN, int WM, int WN, bool GU>
__global__ __launch_bounds__(512, 2) void gemm8p(
    const u16* __restrict__ Ag, const u16* __restrict__ Bg,
    int lda, int ldb, int nt,
    const float* __restrict__ coef, u16* __restrict__ Hout,
    float* __restrict__ Fout, float* __restrict__ Fout2) {
  constexpr int SA = BM / 128;
  constexpr int SB = BN / 128;
  constexpr int BOFF = BM * 64;
  constexpr int SLOT = (BM + BN) * 64;
  __shared__ __align__(16) char lds[4 * SLOT];

  const int tid = threadIdx.x;
  const int l = tid & 63, l31 = l & 31, lh = l >> 5;
  const int wv = tid >> 6;
  const int wr = wv / WN, wc = wv % WN;

  int mT, nT, split = 0;
  if constexpr (GU) {
    int id = blockIdx.x;
    int xcd = id & 7, pos = id >> 3;
    int rG = xcd >> 2, cG = xcd & 3;
    int mL = pos & 15, nL = pos >> 4;
    mT = rG * 16 + mL; nT = cG * 10 + nL;
  } else {
    int id = blockIdx.x;
    int xcd = id & 7, pos = id >> 3;
    int mG = xcd >> 1, cG = xcd & 1;
    split = pos >> 4; int r = pos & 15;
    int mL = r & 3, nL = r >> 2;
    mT = mG * 4 + mL; nT = cG * 4 + nL;
  }
  const int m0 = mT * BM, n0 = nT * BN;
  const int kbase = GU ? 0 : split * 2560;

  const char* gA[SA]; int lA[SA];
  const char* gB[SB]; int lB[SB];
#pragma unroll
  for (int j = 0; j < SA; ++j) {
    int L = (j * 512 + tid) * 16;
    int p = L >> 7, uph = (L >> 4) & 7;
    int usw = uph ^ (p & 7);
    int row = 2 * p + (usw >> 2), ulog = usw & 3;
    gA[j] = (const char*)(Ag + (size_t)(m0 + row) * lda + kbase) + ulog * 16;
    lA[j] = L;
  }
#pragma unroll
  for (int j = 0; j < SB; ++j) {
    int L = (j * 512 + tid) * 16;
    int p = L >> 7, uph = (L >> 4) & 7;
    int usw = uph ^ (p & 7);
    int row = 2 * p + (usw >> 2), ulog = usw & 3;
    gB[j] = (const char*)(Bg + (size_t)(n0 + row) * ldb + kbase) + ulog * 16;
    lB[j] = L;
  }

  // frag offsets: index = m*2+khalf (A) / n*2+khalf (B); u = khalf*2 + lh
  int offA[4], offB[4];
#pragma unroll
  for (int m = 0; m < 2; ++m)
#pragma unroll
    for (int kh = 0; kh < 2; ++kh)
      offA[m * 2 + kh] = swzoff(wr * 64 + m * 32 + l31, kh * 2 + lh);
#pragma unroll
  for (int n = 0; n < 2; ++n)
#pragma unroll
    for (int kh = 0; kh < 2; ++kh)
      offB[n * 2 + kh] = BOFF + swzoff(wc * 64 + n * 32 + l31, kh * 2 + lh);

  f32x16 acc[2][2];
#pragma unroll
  for (int m = 0; m < 2; ++m)
#pragma unroll
    for (int n = 0; n < 2; ++n)
#pragma unroll
      for (int r = 0; r < 16; ++r) acc[m][n][r] = 0.f;

#define STAGE(T)                                                               \
  {                                                                            \
    char* sb_ = lds + (((T) & 3) * SLOT);                                      \
    const int tb_ = (T) * 64;                                                  \
    _Pragma("unroll") for (int j = 0; j < SA; ++j)                             \
        GLOAD16(gA[j] + tb_, sb_ + lA[j]);                                     \
    _Pragma("unroll") for (int j = 0; j < SB; ++j)                             \
        GLOAD16(gB[j] + tb_, sb_ + BOFF + lB[j]);                              \
  }
#define LOADFRAG(AF, BF, T)                                                    \
  {                                                                            \
    char* sb_ = lds + (((T) & 3) * SLOT);                                      \
    _Pragma("unroll") for (int q = 0; q < 4; ++q) {                            \
      AF[q] = *(const bf16x8*)(sb_ + offA[q]);                                 \
      BF[q] = *(const bf16x8*)(sb_ + offB[q]);                                 \
    }                                                                          \
  }
#define MMAC(AF, BF)                                                           \
  {                                                                            \
    __builtin_amdgcn_s_setprio(1);                                             \
    _Pragma("unroll") for (int m = 0; m < 2; ++m)                              \
        _Pragma("unroll") for (int n = 0; n < 2; ++n) {                        \
      acc[m][n] = __builtin_amdgcn_mfma_f32_32x32x16_bf16(                     \
          AF[m * 2 + 0], BF[n * 2 + 0], acc[m][n], 0, 0, 0);                   \
      acc[m][n] = __builtin_amdgcn_mfma_f32_32x32x16_bf16(                     \
          AF[m * 2 + 1], BF[n * 2 + 1], acc[m][n], 0, 0, 0);                   \
    }                                                                          \
    __builtin_amdgcn_s_setprio(0);                                             \
  }
// wait: confirm slot t+1 landed (counted, never over-drains; exact at tail)
#define WAITSTEP(T)                                                            \
  {                                                                            \
    if ((T) + 3 < nt) {                                                        \
      STAGE((T) + 3);                                                          \
      asm volatile("s_waitcnt vmcnt(6)" ::: "memory");                         \
    } else if ((T) + 3 == nt) {                                                \
      asm volatile("s_waitcnt vmcnt(3)" ::: "memory");                         \
    } else {                                                                   \
      asm volatile("s_waitcnt vmcnt(0)" ::: "memory");                         \
    }                                                                          \
  }

  bf16x8 aE[4], bE[4], aO[4], bO[4];

  STAGE(0); STAGE(1); STAGE(2);
  asm volatile("s_waitcnt vmcnt(6)" ::: "memory");
  __builtin_amdgcn_s_barrier();
  LOADFRAG(aE, bE, 0);

  for (int t = 0; t < nt; t += 2) {
    // even: compute frags(t)=E, prefetch frags(t+1)->O
    WAITSTEP(t);
    __builtin_amdgcn_s_barrier();      // slot t+1 confirmed
    LOADFRAG(aO, bO, t + 1);           // t+1 <= nt-1 always (nt even)
    MMAC(aE, bE);
    asm volatile("" ::: "memory");
    __builtin_amdgcn_s_barrier();
    // odd: compute frags(t+1)=O, prefetch frags(t+2)->E
    WAITSTEP(t + 1);
    __builtin_amdgcn_s_barrier();      // slot t+2 confirmed (if exists)
    if (t + 2 < nt) LOADFRAG(aE, bE, t + 2);
    MMAC(aO, bO);
    asm volatile("" ::: "memory");
    __builtin_amdgcn_s_barrier();
  }
#undef STAGE
#undef LOADFRAG
#undef MMAC
#undef WAITSTEP

  // C/D layout (32x32): col = l&31, row = (reg&3) + 8*(reg>>2) + 4*(l>>5)
  const int crb = 4 * lh;
  if constexpr (GU) {
    const int rbW = m0 + wr * 64;
    const int hb = (n0 + wc * 64) >> 1;
    const int colh = hb + l31;
    const float sc0 = (colh < 4096) ? 0.f : 1.f;  // placeholder; per-row below
#pragma unroll
    for (int m = 0; m < 2; ++m)
#pragma unroll
      for (int r = 0; r < 16; ++r) {
        int row = rbW + m * 32 + (r & 3) + 8 * (r >> 2) + crb;
        float g = acc[m][0][r];
        float u = acc[m][1][r];
        float sc = (colh < 4096) ? coef[row * 8 + (colh >> 9)] : 1.f;
        (void)sc0;
        Hout[(size_t)row * 5120 + colh] = f2bf(g / (1.f + __expf(-g)) * u * sc);
      }
  } else {
    float* dst = split ? Fout2 : Fout;
    const int rbW = m0 + wr * 64;
    const int cbW = n0 + wc * 64;
#pragma unroll
    for (int m = 0; m < 2; ++m)
#pragma unroll
      for (int n = 0; n < 2; ++n)
#pragma unroll
        for (int r = 0; r < 16; ++r) {
          int row = rbW + m * 32 + (r & 3) + 8 * (r >> 2) + crb;
          dst[(size_t)row * 1024 + cbW + n * 32 + l31] = acc[m][n][r];
        }
  }
}

// ---------------- split-K reduce: out += p1 ----------------
__global__ void reduce_add(float* __restrict__ out, const float* __restrict__ p1) {
  int i = blockIdx.x * 256 + threadIdx.x;
  float4 a = ((const float4*)out)[i];
  float4 b = ((const float4*)p1)[i];
  a.x += b.x; a.y += b.y; a.z += b.z; a.w += b.w;
  ((float4*)out)[i] = a;
}

extern "C" void kernel_launch(void* const* d_in, const int* in_sizes, int n_in,
                              void* d_out, int out_size, void* d_ws, size_t ws_size,
                              hipStream_t stream) {
  const float* x  = (const float*)d_in[0];
  const float* rw = (const float*)d_in[1];
  const float* eg = (const float*)d_in[2];
  const float* eu = (const float*)d_in[3];
  const float* ed = (const float*)d_in[4];
  const float* sg = (const float*)d_in[5];
  const float* su = (const float*)d_in[6];
  const float* sd = (const float*)d_in[7];
  float* out = (float*)d_out;

  char* ws = (char*)d_ws;
  u16*   Xb   = (u16*)(ws);                    // 8,388,608 B
  u16*   WpT  = (u16*)(ws + 8388608);          // 20,971,520 B
  u16*   WdT  = (u16*)(ws + 29360128);         // 10,485,760 B
  u16*   Hm   = (u16*)(ws + 39845888);         // 41,943,040 B
  float* coef = (float*)(ws + 81788928);       // 131,072 B
  float* p1   = (float*)(ws);                  // 16 MB split-K partial (overlays Xb/WpT)

  mega<<<6912, 256, 0, stream>>>(x, rw, eg, eu, ed, sg, su, sd, Xb, WpT, WdT, coef);

  gemm8p<128, 256, 2, 4, true><<<1280, 512, 0, stream>>>(
      Xb, WpT, 1024, 1024, 32, coef, Hm, nullptr, nullptr);

  gemm8p<256, 128, 4, 2, false><<<256, 512, 0, stream>>>(
      Hm, WdT, 5120, 5120, 80, nullptr, nullptr, out, p1);

  reduce_add<<<4096, 256, 0, stream>>>(out, p1);
}